// Round 13
// baseline (303.770 us; speedup 1.0000x reference)
//
#include <hip/hip_runtime.h>
#include <hip/hip_fp16.h>

#define N_NODES 100000
#define N_EDGES 1600000
#define D_FEAT 32
#define CAP 31                        // entries per row; row[0] is the count
#define NPASS 8                       // dst-range passes (R8/R12: optimum)
#define NODES_PER_P (N_NODES / NPASS)             // 12500
#define EDGE_THREADS (N_EDGES / 4)                // 400000 (4 edges/thread)
#define EDGE_BLOCKS ((EDGE_THREADS + 255) / 256)  // 1563

typedef int   __attribute__((ext_vector_type(4))) i32x4;
typedef float __attribute__((ext_vector_type(4))) f32x4;

// ---- K0 (fused): weighted fp16 table + zero out + zero row-counters ----
__global__ __launch_bounds__(256) void lgc_weight(
    const f32x4* __restrict__ feats4,   // [N_NODES * 8]
    const float* __restrict__ cj,       // [N_NODES]
    __half2*     __restrict__ w2,       // [N_NODES * 16]
    int*         __restrict__ brow,     // [N_NODES * 32] bucket rows
    f32x4*       __restrict__ out4)     // [N_NODES * 8] -> zeroed here
{
    int tid = blockIdx.x * 256 + threadIdx.x;   // exactly 800000
    float c = cj[tid >> 3];
    f32x4 v = __builtin_nontemporal_load(&feats4[tid]);
    w2[tid * 2 + 0] = __floats2half2_rn(v.x * c, v.y * c);
    w2[tid * 2 + 1] = __floats2half2_rn(v.z * c, v.w * c);
    f32x4 z = (f32x4)(0.f);
    __builtin_nontemporal_store(z, &out4[tid]);      // zero spill base
    if (tid < N_NODES) brow[(size_t)tid * 32] = 0;   // zero count word
}

__device__ __forceinline__ void spill_row(const __half* __restrict__ weighted,
                                          float* __restrict__ out, int s, int d)
{
    const __half* row = weighted + (size_t)s * D_FEAT;
    float* o = out + (size_t)d * D_FEAT;
    for (int f = 0; f < D_FEAT; ++f) atomicAdd(o + f, __half2float(row[f]));
}

// ---- K1: bucket build. Row layout [cnt | 31 entries] so the entry store hits
// the L2 line the cnt-atomic just pulled. 8 dst-range passes, NT idx loads.
__global__ __launch_bounds__(256) void lgc_bucket(
    const i32x4*  __restrict__ dst4,      // [N_EDGES/4]
    const i32x4*  __restrict__ src4,      // [N_EDGES/4]
    const __half* __restrict__ weighted,  // spill path only
    int*          __restrict__ brow,      // [N_NODES * 32]
    float*        __restrict__ out)       // pre-zeroed; overflow spill target
{
    int x  = blockIdx.x % NPASS;          // dst-range this block handles
    int lb = blockIdx.x / NPASS;
    int t  = lb * 256 + threadIdx.x;
    if (t >= EDGE_THREADS) return;

    const int lo = x * NODES_PER_P;
    const int hi = lo + NODES_PER_P;

    i32x4 d4 = __builtin_nontemporal_load(&dst4[t]);
    bool ix = (d4.x >= lo) & (d4.x < hi);
    bool iy = (d4.y >= lo) & (d4.y < hi);
    bool iz = (d4.z >= lo) & (d4.z < hi);
    bool iw = (d4.w >= lo) & (d4.w < hi);
    if (!(ix | iy | iz | iw)) return;

    i32x4 s4 = __builtin_nontemporal_load(&src4[t]);
    int ds[4] = {d4.x, d4.y, d4.z, d4.w};
    int ss[4] = {s4.x, s4.y, s4.z, s4.w};
    bool in[4] = {ix, iy, iz, iw};

    #pragma unroll
    for (int k = 0; k < 4; ++k) {
        if (!in[k]) continue;
        int d = ds[k], s = ss[k];
        int* row = brow + (size_t)d * 32;
        int pos = atomicAdd(row, 1);
        if (pos < CAP) {
            row[1 + pos] = s;                 // same/adjacent line as cnt
        } else {
            spill_row(weighted, out, s, d);   // statistically never (~20 edges)
        }
    }
}

// ---- K2: gather-sum. 4 lanes/node; whole 128B row (cnt+entries) prefetched as
// 8 unconditional int4 loads (2-deep chain: row -> feats). 8-deep feat batching.
__global__ __launch_bounds__(256) void lgc_gather(
    const uint4* __restrict__ w4,        // [N_NODES * 4] 16B units (8 fp16 feats)
    const float* __restrict__ ci,
    const i32x4* __restrict__ brow4,     // [N_NODES * 8]
    f32x4*       __restrict__ out4)      // [N_NODES * 8]
{
    int tid = blockIdx.x * 256 + threadIdx.x;
    if (tid >= N_NODES * 4) return;
    int n = tid >> 2;
    int q = tid & 3;                     // 8-feat slice

    const i32x4* b4 = brow4 + (size_t)n * 8;
    i32x4 r[8];
    #pragma unroll
    for (int j = 0; j < 8; ++j)
        r[j] = __builtin_nontemporal_load(&b4[j]);   // all independent

    int c = ((const int*)r)[0];
    if (c > CAP) c = CAP;
    const int* ent = ((const int*)r) + 1;

    float acc[8] = {0.f, 0.f, 0.f, 0.f, 0.f, 0.f, 0.f, 0.f};

    #pragma unroll
    for (int b = 0; b < 4; ++b) {
        const int base = b * 8;
        if (base < c) {
            int m = c - base;                  // 1..8 valid edges this batch
            uint4 v[8];
            #pragma unroll
            for (int t = 0; t < 8; ++t) {      // phase 1: issue 8 loads
                if (t < m) {
                    int s = ent[base + t];     // compile-time reg index
                    v[t] = w4[(size_t)s * 4 + q];
                }
            }
            #pragma unroll
            for (int t = 0; t < 8; ++t) {      // phase 2: convert + accumulate
                if (t < m) {
                    unsigned ux = v[t].x, uy = v[t].y, uz = v[t].z, uw = v[t].w;
                    float2 f0 = __half22float2(*(__half2*)&ux);
                    float2 f1 = __half22float2(*(__half2*)&uy);
                    float2 f2 = __half22float2(*(__half2*)&uz);
                    float2 f3 = __half22float2(*(__half2*)&uw);
                    acc[0] += f0.x; acc[1] += f0.y; acc[2] += f1.x; acc[3] += f1.y;
                    acc[4] += f2.x; acc[5] += f2.y; acc[6] += f3.x; acc[7] += f3.y;
                }
            }
        }
    }

    float sc = ci[n];
    size_t ob = (size_t)n * 8 + q * 2;
    f32x4 o0 = __builtin_nontemporal_load(&out4[ob]);      // spill base (normally 0)
    f32x4 o1 = __builtin_nontemporal_load(&out4[ob + 1]);
    f32x4 a0 = {acc[0], acc[1], acc[2], acc[3]};
    f32x4 a1 = {acc[4], acc[5], acc[6], acc[7]};
    __builtin_nontemporal_store((a0 + o0) * sc, &out4[ob]);
    __builtin_nontemporal_store((a1 + o1) * sc, &out4[ob + 1]);
}

// ---------------- round-1 fallback path (only if ws too small) ----------------
__global__ __launch_bounds__(256) void lgc_scatter(
    const float4* __restrict__ src_feats4,
    const float*  __restrict__ cj,
    const int*    __restrict__ src_idx,
    const int*    __restrict__ dst_idx,
    float*        __restrict__ out)
{
    long tid = (long)blockIdx.x * blockDim.x + threadIdx.x;
    const long total = (long)N_EDGES * 8;
    if (tid >= total) return;
    int e  = (int)(tid >> 3);
    int f4 = (int)(tid & 7);
    int s = src_idx[e];
    int d = dst_idx[e];
    float c = cj[s];
    float4 v = src_feats4[s * 8 + f4];
    float* o = out + (size_t)d * D_FEAT + f4 * 4;
    atomicAdd(o + 0, v.x * c);
    atomicAdd(o + 1, v.y * c);
    atomicAdd(o + 2, v.z * c);
    atomicAdd(o + 3, v.w * c);
}

__global__ __launch_bounds__(256) void lgc_scale(
    float4*       __restrict__ out4,
    const float*  __restrict__ ci)
{
    int tid = blockIdx.x * blockDim.x + threadIdx.x;
    const int total = N_NODES * 8;
    if (tid >= total) return;
    float c = ci[tid >> 3];
    float4 v = out4[tid];
    v.x *= c; v.y *= c; v.z *= c; v.w *= c;
    out4[tid] = v;
}

extern "C" void kernel_launch(void* const* d_in, const int* in_sizes, int n_in,
                              void* d_out, int out_size, void* d_ws, size_t ws_size,
                              hipStream_t stream) {
    const float* src_feats = (const float*)d_in[0];   // [100000, 32] f32
    const float* cj        = (const float*)d_in[1];   // [100000, 1]
    const float* ci        = (const float*)d_in[2];   // [100000, 1]
    const int*   src_idx   = (const int*)d_in[3];     // [1600000]
    const int*   dst_idx   = (const int*)d_in[4];     // [1600000]
    float*       out       = (float*)d_out;           // [100000, 32] f32

    // ws layout: brow[N_NODES*32 ints, 12.8MB] | weighted[N_NODES*32 fp16, 6.4MB]
    const size_t brow_ints   = (size_t)N_NODES * 32;
    const size_t wfeat_bytes = (size_t)N_NODES * D_FEAT * sizeof(__half);
    const size_t need = brow_ints * 4 + wfeat_bytes;

    if (ws_size >= need) {
        int*    brow     = (int*)d_ws;
        __half* weighted = (__half*)(brow + brow_ints);

        lgc_weight<<<(N_NODES * 8) / 256, 256, 0, stream>>>(
            (const f32x4*)src_feats, cj, (__half2*)weighted, brow,
            (f32x4*)out);

        lgc_bucket<<<NPASS * EDGE_BLOCKS, 256, 0, stream>>>(
            (const i32x4*)dst_idx, (const i32x4*)src_idx, weighted,
            brow, out);

        lgc_gather<<<(N_NODES * 4 + 255) / 256, 256, 0, stream>>>(
            (const uint4*)weighted, ci, (const i32x4*)brow, (f32x4*)out);
    } else {
        hipMemsetAsync(out, 0, (size_t)out_size * sizeof(float), stream);
        {
            const long total = (long)N_EDGES * 8;
            const int grid = (int)((total + 255) / 256);
            lgc_scatter<<<grid, 256, 0, stream>>>((const float4*)src_feats, cj,
                                                  src_idx, dst_idx, out);
        }
        {
            const int grid = (N_NODES * 8 + 255) / 256;
            lgc_scale<<<grid, 256, 0, stream>>>((float4*)out, ci);
        }
    }
}